// Round 2
// baseline (899.827 us; speedup 1.0000x reference)
//
#include <hip/hip_runtime.h>
#include <hip/hip_bf16.h>

typedef unsigned short u16;
typedef unsigned int   u32;

namespace {
constexpr int Kc  = 24;
constexpr int CPJ = 128;
constexpr int TD  = 128;
constexpr int Tc  = 4096;
constexpr int NT  = 4;    // consecutive t per block (write-coalescing group)
constexpr float EPS   = 1e-5f;
constexpr float SCALE = 0.08838834764831845f;  // 128^-0.5

constexpr int AS = 136;  // bf16 row stride for 32-row token-major tiles
constexpr int VS = 40;   // row stride for vT[128][.] and Pb[32][.]
constexpr int SS = 36;   // f32 row stride for scores

// packed-weight section offsets (bf16 elems): fragment chunks of 512 elems,
// chunk (ntile,kstep): elem[lane*8+j] = W[kstep*32+(lane>>4)*8+j][ntile*16+(lane&15)]
constexpr int OFF_TOK  = 0;
constexpr int OFF_QKV  = 16384;
constexpr int OFF_PROJ = 65536;
constexpr int OFF_FROM = 81920;
constexpr int WTOT     = 98304;

typedef __attribute__((ext_vector_type(8))) short short8;
typedef __attribute__((ext_vector_type(4))) float f32x4;

__device__ u16 g_wpack[WTOT];

__device__ __forceinline__ float b2f(u16 u) {
  union { u32 i; float f; } c; c.i = ((u32)u) << 16; return c.f;
}
__device__ __forceinline__ u16 f2b(float f) {
  __hip_bfloat16 h = __float2bfloat16(f);
  u16 u; __builtin_memcpy(&u, &h, 2); return u;
}
template <bool F32> __device__ __forceinline__ float ld1(const void* p, int i) {
  return F32 ? ((const float*)p)[i] : b2f(((const u16*)p)[i]);
}
__device__ __forceinline__ f32x4 mfma16(short8 a, short8 b, f32x4 c) {
  return __builtin_amdgcn_mfma_f32_16x16x32_bf16(a, b, c, 0, 0, 0);
}
// channel->slab-slot swizzle: XOR bit4 with channel bit9 (== joint-row bit2) so
// the 4 quads of the final-GEMM staging store hit 2 disjoint 16-bank sets.
__device__ __forceinline__ int slot(int c) { return c ^ (((c >> 9) & 1) << 4); }

// block-uniform dtype sniff: f32 storage -> low mantissa words decode huge as bf16
template <int NTH>
__device__ bool sniff_f32(const u16* x, float* red, int tid) {
  float m = 0.f;
  for (int i = tid; i < 1024; i += NTH) m = fmaxf(m, fabsf(b2f(x[i])));
  red[tid] = m;
  __syncthreads();
  if (tid < 32) {
    float mm = red[tid];
    for (int s = tid + 32; s < NTH; s += 32) mm = fmaxf(mm, red[s]);
    red[tid] = mm;
  }
  __syncthreads();
  if (tid == 0) {
    float mm = red[0];
    for (int s = 1; s < 32; ++s) mm = fmaxf(mm, red[s]);
    red[0] = mm;
  }
  __syncthreads();
  return red[0] > 1e8f;
}
}  // namespace

// ---------------- weight packing kernel (runs every launch) ----------------
template <bool F32>
__device__ void pack_body(const void* Wtok, const void* Wqkv, const void* Wproj,
                          const void* Wfrom, int gid) {
  const void* W; int Nw, base;
  if (gid < OFF_QKV)       { W = Wtok;  Nw = 128; base = OFF_TOK;  }
  else if (gid < OFF_PROJ) { W = Wqkv;  Nw = 384; base = OFF_QKV;  }
  else if (gid < OFF_FROM) { W = Wproj; Nw = 128; base = OFF_PROJ; }
  else                     { W = Wfrom; Nw = 128; base = OFF_FROM; }
  const int e = gid - base, chunk = e >> 9, rem = e & 511, lane = rem >> 3, j = rem & 7;
  const int ntile = chunk >> 2, kstep = chunk & 3;
  const int n = ntile * 16 + (lane & 15);
  const int k = kstep * 32 + (lane >> 4) * 8 + j;
  g_wpack[gid] = F32 ? f2b(((const float*)W)[k * Nw + n]) : ((const u16*)W)[k * Nw + n];
}

__global__ __launch_bounds__(256) void wan_pack_kernel(
    const void* x, const void* Wtok, const void* Wqkv, const void* Wproj,
    const void* Wfrom) {
  __shared__ float red[256];
  const int tid = threadIdx.x;
  const bool f32m = sniff_f32<256>((const u16*)x, red, tid);
  const int gid = blockIdx.x * 256 + tid;
  if (gid < WTOT) {
    if (f32m) pack_body<true>(Wtok, Wqkv, Wproj, Wfrom, gid);
    else      pack_body<false>(Wtok, Wqkv, Wproj, Wfrom, gid);
  }
}

// ---------------- main kernel ----------------
// Two independent 4-wave teams per block; each team runs the full per-t
// pipeline on its own tile set. Shared io slab covers NT=4 consecutive t.
struct __align__(16) TeamSmem {
  u16 xt[32 * AS];     // current-t x tile bf16 (+ residual); rows 24..31 zero
  u16 tokb[32 * AS];   // tok -> later O (attn@v)
  u16 qb[32 * AS];     // q -> later out2
  u16 kb[32 * AS];
  u16 vt[128 * VS];    // v transposed [dim][token]
  u16 Pb[32 * VS];     // probs, K-padded with zeros
  float Sf[32 * SS];   // scores; tm[0].Sf overlays the sniff reduction (512 f)
};                     // 52224 B

struct __align__(16) Smem {
  float slab[NT * 3072];  // 48 KiB: x-in / y-out staging, io-dtype, t-major
  TeamSmem tm[2];
};                        // 153600 B -> 1 block/CU, 8 waves/CU (2/SIMD)

// C[32x128] = A @ Wpacked + bias, C stored bf16 row-major stride AS.
template <bool F32>
__device__ __forceinline__ void gemmA(const u16* A, const u16* wp, const void* bias,
                                      u16* C, int mtile, int wn, int l16, int quad,
                                      int lane) {
  const u16* arow = A + (mtile * 16 + l16) * AS + quad * 8;
  short8 af[4];
  #pragma unroll
  for (int ks = 0; ks < 4; ++ks) af[ks] = *(const short8*)(arow + ks * 32);
  #pragma unroll
  for (int i = 0; i < 4; ++i) {
    const int ntile = wn * 4 + i;
    const float bv = ld1<F32>(bias, ntile * 16 + l16);
    f32x4 acc = {bv, bv, bv, bv};
    #pragma unroll
    for (int ks = 0; ks < 4; ++ks) {
      short8 bf = *(const short8*)(wp + (ntile * 4 + ks) * 512 + lane * 8);
      acc = mfma16(af[ks], bf, acc);
    }
    u16* p = C + (mtile * 16 + quad * 4) * AS + ntile * 16 + l16;
    p[0] = f2b(acc[0]); p[AS] = f2b(acc[1]);
    p[2 * AS] = f2b(acc[2]); p[3 * AS] = f2b(acc[3]);
  }
}

template <bool F32>
__device__ void main_body(Smem& s, int tid, long long xbase, const void* x,
                          const void* btok, const void* gnorm, const void* bqkv,
                          const void* bproj, const void* bfrom, void* y) {
  const int team = tid >> 8, ttid = tid & 255;
  TeamSmem& tm = s.tm[team];
  const int lane = ttid & 63, wid = ttid >> 6;
  const int l16 = lane & 15, quad = lane >> 4;
  const int mtile = wid & 1, wn = wid >> 1;

  // ---- once: zero Pb (K-pad safety) + xt pad rows (per team) -----------
  for (int i = ttid; i < 32 * VS; i += 256) tm.Pb[i] = 0;
  for (int i = ttid; i < 8 * AS; i += 256) tm.xt[24 * AS + i] = 0;

  // ---- stage x slab [NT][3072] once: 16B contiguous per channel --------
  if (F32) {
    const float* xf = (const float*)x + xbase;
    #pragma unroll
    for (int m = 0; m < 6; ++m) {
      const int c = tid + 512 * m;
      const float4 v = *(const float4*)(xf + (long long)c * Tc);
      float* dst = s.slab + slot(c);
      dst[0] = v.x; dst[3072] = v.y; dst[2 * 3072] = v.z; dst[3 * 3072] = v.w;
    }
  } else {
    const u16* xh = (const u16*)x + xbase;
    u16* sl = (u16*)s.slab;
    #pragma unroll
    for (int m = 0; m < 6; ++m) {
      const int c = tid + 512 * m;
      const ushort4 v = *(const ushort4*)(xh + (long long)c * Tc);
      u16* dst = sl + slot(c);
      dst[0] = v.x; dst[3072] = v.y; dst[2 * 3072] = v.z; dst[3 * 3072] = v.w;
    }
  }

  #pragma unroll 1
  for (int it = 0; it < 2; ++it) {
    const int j = team * 2 + it;  // this team's t-slot within the quad
    __syncthreads();  // slab ready / prev iteration fully consumed

    // ---- copy slab col j -> xt (bf16 row-major token tile) -------------
    #pragma unroll
    for (int m = 0; m < 3; ++m) {
      const int c4 = (ttid + 256 * m) * 4;   // 4 consecutive channels
      const int sb = slot(c4);               // slot() preserves 4-contiguity
      ushort4 o;
      if (F32) {
        const float4 v = *(const float4*)(s.slab + j * 3072 + sb);
        o.x = f2b(v.x); o.y = f2b(v.y); o.z = f2b(v.z); o.w = f2b(v.w);
      } else {
        o = *(const ushort4*)((const u16*)s.slab + j * 3072 + sb);
      }
      *(ushort4*)(tm.xt + (c4 >> 7) * AS + (c4 & 127)) = o;
    }
    __syncthreads();

    // ---- tok = xt @ Wtok + btok ----------------------------------------
    gemmA<F32>(tm.xt, g_wpack + OFF_TOK, btok, tm.tokb, mtile, wn, l16, quad, lane);
    __syncthreads();

    // ---- RMSNorm rows 0..23 (in-place bf16, 2 barriers) ----------------
    float* partial = tm.Sf;  // 192 floats
    if (ttid < 192) {
      const int row = ttid >> 3, sub = ttid & 7;
      const u16* p = tm.tokb + row * AS + sub * 16;
      float ss = 0.f;
      #pragma unroll
      for (int d = 0; d < 16; ++d) { const float v = b2f(p[d]); ss += v * v; }
      partial[ttid] = ss;
    }
    __syncthreads();
    if (ttid < 192) {
      const int row = ttid >> 3, sub = ttid & 7;
      float ss = 0.f;
      #pragma unroll
      for (int u = 0; u < 8; ++u) ss += partial[row * 8 + u];
      const float rs = rsqrtf(ss * (1.0f / TD) + EPS);
      u16* p = tm.tokb + row * AS + sub * 16;
      #pragma unroll
      for (int d = 0; d < 16; ++d)
        p[d] = f2b(b2f(p[d]) * rs * ld1<F32>(gnorm, sub * 16 + d));
    }
    __syncthreads();

    // ---- qkv = tok @ Wqkv + bqkv; v stored transposed ------------------
    {
      const u16* wp = g_wpack + OFF_QKV;
      const u16* arow = tm.tokb + (mtile * 16 + l16) * AS + quad * 8;
      short8 af[4];
      #pragma unroll
      for (int ks = 0; ks < 4; ++ks) af[ks] = *(const short8*)(arow + ks * 32);
      for (int g = 0; g < 3; ++g) {
        #pragma unroll
        for (int i = 0; i < 4; ++i) {
          const int nn = wn + i * 2;       // 0..7 within segment
          const int ntile = g * 8 + nn;    // 0..23
          const float bv = ld1<F32>(bqkv, ntile * 16 + l16);
          f32x4 acc = {bv, bv, bv, bv};
          #pragma unroll
          for (int ks = 0; ks < 4; ++ks) {
            short8 bf = *(const short8*)(wp + (ntile * 4 + ks) * 512 + lane * 8);
            acc = mfma16(af[ks], bf, acc);
          }
          if (g == 2) {
            ushort4 v4 = {f2b(acc[0]), f2b(acc[1]), f2b(acc[2]), f2b(acc[3])};
            *reinterpret_cast<ushort4*>(tm.vt + (nn * 16 + l16) * VS + mtile * 16 +
                                        quad * 4) = v4;
          } else {
            u16* dst = g ? tm.kb : tm.qb;
            u16* p = dst + (mtile * 16 + quad * 4) * AS + nn * 16 + l16;
            p[0] = f2b(acc[0]); p[AS] = f2b(acc[1]);
            p[2 * AS] = f2b(acc[2]); p[3 * AS] = f2b(acc[3]);
          }
        }
      }
    }
    __syncthreads();

    // ---- S = q @ k^T * SCALE (one 16x16 tile per wave) -----------------
    {
      // fragment loads MUST include the per-quad k-offset (+ quad*8)
      const u16* qrow = tm.qb + (mtile * 16 + l16) * AS + quad * 8;
      const u16* krow = tm.kb + (wn * 16 + l16) * AS + quad * 8;
      f32x4 acc = {0.f, 0.f, 0.f, 0.f};
      #pragma unroll
      for (int ks = 0; ks < 4; ++ks) {
        short8 a = *(const short8*)(qrow + ks * 32);
        short8 b = *(const short8*)(krow + ks * 32);
        acc = mfma16(a, b, acc);
      }
      float* sp = tm.Sf + (mtile * 16 + quad * 4) * SS + wn * 16 + l16;
      sp[0] = acc[0] * SCALE; sp[SS] = acc[1] * SCALE;
      sp[2 * SS] = acc[2] * SCALE; sp[3 * SS] = acc[3] * SCALE;
    }
    __syncthreads();

    // ---- softmax rows 0..23 over cols 0..23 -> Pb (bf16, zero-padded) --
    if (ttid < 24) {
      const float* sr = tm.Sf + ttid * SS;
      float mx = -1e30f;
      #pragma unroll
      for (int jj = 0; jj < 24; ++jj) mx = fmaxf(mx, sr[jj]);
      float sum = 0.f; float e[24];
      #pragma unroll
      for (int jj = 0; jj < 24; ++jj) { e[jj] = expf(sr[jj] - mx); sum += e[jj]; }
      const float inv = 1.0f / sum;
      u16* pr = tm.Pb + ttid * VS;
      #pragma unroll
      for (int jj = 0; jj < 24; ++jj) pr[jj] = f2b(e[jj] * inv);
    }
    __syncthreads();

    // ---- O = P @ v (K=32, single MFMA per tile) -> tokb ----------------
    {
      short8 ap = *(const short8*)(tm.Pb + (mtile * 16 + l16) * VS + quad * 8);
      #pragma unroll
      for (int i = 0; i < 4; ++i) {
        const int nt = wn * 4 + i;
        short8 bv = *(const short8*)(tm.vt + (nt * 16 + l16) * VS + quad * 8);
        f32x4 acc = {0.f, 0.f, 0.f, 0.f};
        acc = mfma16(ap, bv, acc);
        u16* p = tm.tokb + (mtile * 16 + quad * 4) * AS + nt * 16 + l16;
        p[0] = f2b(acc[0]); p[AS] = f2b(acc[1]);
        p[2 * AS] = f2b(acc[2]); p[3 * AS] = f2b(acc[3]);
      }
    }
    __syncthreads();

    // ---- out2 = O @ Wproj + bproj -> qb --------------------------------
    gemmA<F32>(tm.tokb, g_wpack + OFF_PROJ, bproj, tm.qb, mtile, wn, l16, quad, lane);
    __syncthreads();

    // ---- out3 = out2 @ Wfrom + bfrom; stage y = x + out3 in slab -------
    {
      const u16* arow = tm.qb + (mtile * 16 + l16) * AS + quad * 8;
      const u16* wp = g_wpack + OFF_FROM;
      short8 af[4];
      #pragma unroll
      for (int ks = 0; ks < 4; ++ks) af[ks] = *(const short8*)(arow + ks * 32);
      #pragma unroll
      for (int i = 0; i < 4; ++i) {
        const int ntile = wn * 4 + i;
        const float bv = ld1<F32>(bfrom, ntile * 16 + l16);
        f32x4 acc = {bv, bv, bv, bv};
        #pragma unroll
        for (int ks = 0; ks < 4; ++ks) {
          short8 bf = *(const short8*)(wp + (ntile * 4 + ks) * 512 + lane * 8);
          acc = mfma16(af[ks], bf, acc);
        }
        const int row0 = mtile * 16 + quad * 4;
        if (row0 < 24) {
          #pragma unroll
          for (int r = 0; r < 4; ++r) {
            const int row = row0 + r;
            const int cc = ntile * 16 + l16;
            const float res = b2f(tm.xt[row * AS + cc]) + acc[r];
            const int ch = row * CPJ + cc;
            if (F32) s.slab[j * 3072 + slot(ch)] = res;
            else     ((u16*)s.slab)[j * 3072 + slot(ch)] = f2b(res);
          }
        }
      }
    }
    // loop-top barrier separates this from next iteration's xt overwrite
  }
  __syncthreads();

  // ---- write out slab -> y: 16B contiguous per channel -----------------
  if (F32) {
    float* yf = (float*)y + xbase;
    #pragma unroll
    for (int m = 0; m < 6; ++m) {
      const int c = tid + 512 * m;
      const int sc = slot(c);
      float4 a;
      a.x = s.slab[0 * 3072 + sc]; a.y = s.slab[1 * 3072 + sc];
      a.z = s.slab[2 * 3072 + sc]; a.w = s.slab[3 * 3072 + sc];
      *(float4*)(yf + (long long)c * Tc) = a;
    }
  } else {
    u16* yh = (u16*)y + xbase;
    const u16* sl = (const u16*)s.slab;
    #pragma unroll
    for (int m = 0; m < 6; ++m) {
      const int c = tid + 512 * m;
      const int sc = slot(c);
      ushort4 v;
      v.x = sl[0 * 3072 + sc]; v.y = sl[1 * 3072 + sc];
      v.z = sl[2 * 3072 + sc]; v.w = sl[3 * 3072 + sc];
      *(ushort4*)(yh + (long long)c * Tc) = v;
    }
  }
}

__global__ __launch_bounds__(512, 2) void wan_main_kernel(
    const void* x, const void* btok, const void* gnorm, const void* bqkv,
    const void* bproj, const void* bfrom, void* y) {
  __shared__ Smem s;
  const int tid = threadIdx.x;
  // XCD-aware swizzle over t-quads: 4096 blocks = 8 XCDs x 512 contiguous
  // quads, so adjacent-t blocks share an XCD L2 for read/write line merge.
  const int id = blockIdx.x;
  const int q = (id & 7) * 512 + (id >> 3);
  const int b = q >> 10, t0 = (q & 1023) << 2;
  const long long xbase = (long long)b * (Kc * CPJ) * Tc + t0;

  const bool f32m = sniff_f32<512>((const u16*)x, s.tm[0].Sf, tid);
  if (f32m)
    main_body<true>(s, tid, xbase, x, btok, gnorm, bqkv, bproj, bfrom, y);
  else
    main_body<false>(s, tid, xbase, x, btok, gnorm, bqkv, bproj, bfrom, y);
}

extern "C" void kernel_launch(void* const* d_in, const int* in_sizes, int n_in,
                              void* d_out, int out_size, void* d_ws, size_t ws_size,
                              hipStream_t stream) {
  wan_pack_kernel<<<384, 256, 0, stream>>>(d_in[0], d_in[1], d_in[4], d_in[6],
                                           d_in[8]);
  wan_main_kernel<<<4096, 512, 0, stream>>>(d_in[0], d_in[2], d_in[3], d_in[5],
                                            d_in[7], d_in[9], d_out);
}

// Round 3
// 624.064 us; speedup vs baseline: 1.4419x; 1.4419x over previous
//
#include <hip/hip_runtime.h>
#include <hip/hip_bf16.h>

typedef unsigned short u16;
typedef unsigned int   u32;

namespace {
constexpr int Kc  = 24;
constexpr int CPJ = 128;
constexpr int TD  = 128;
constexpr int Tc  = 4096;
constexpr int NT  = 4;    // consecutive t per block, packed into one 96-row tile
constexpr float EPS   = 1e-5f;
constexpr float SCALE = 0.08838834764831845f;  // 128^-0.5

constexpr int AS = 136;  // bf16 row stride, 96-row packed tiles (272 B rows)
constexpr int VS = 40;   // row stride for vt[dim][token] and P[row][token] (80 B)
constexpr int SS = 34;   // f32 row stride for scores (136 B)

// packed-weight section offsets (bf16 elems): fragment chunks of 512 elems,
// chunk (ntile,kstep): elem[lane*8+j] = W[kstep*32+(lane>>4)*8+j][ntile*16+(lane&15)]
constexpr int OFF_TOK  = 0;
constexpr int OFF_QKV  = 16384;
constexpr int OFF_PROJ = 65536;
constexpr int OFF_FROM = 81920;
constexpr int WTOT     = 98304;

typedef __attribute__((ext_vector_type(8))) short short8;
typedef __attribute__((ext_vector_type(4))) float f32x4;

__device__ __align__(16) u16 g_wpack[WTOT];

__device__ __forceinline__ float b2f(u16 u) {
  union { u32 i; float f; } c; c.i = ((u32)u) << 16; return c.f;
}
__device__ __forceinline__ u16 f2b(float f) {
  __hip_bfloat16 h = __float2bfloat16(f);
  u16 u; __builtin_memcpy(&u, &h, 2); return u;
}
template <bool F32> __device__ __forceinline__ float ld1(const void* p, int i) {
  return F32 ? ((const float*)p)[i] : b2f(((const u16*)p)[i]);
}
__device__ __forceinline__ f32x4 mfma16(short8 a, short8 b, f32x4 c) {
  return __builtin_amdgcn_mfma_f32_16x16x32_bf16(a, b, c, 0, 0, 0);
}
// channel->slab-slot swizzle (bijective): spreads final-GEMM staging stores
__device__ __forceinline__ int slot(int c) { return c ^ (((c >> 9) & 1) << 4); }
// div by 24 for idx < 96
__device__ __forceinline__ int div24(int v) { return (v * 2731) >> 16; }

// block-uniform dtype sniff: f32 storage -> low mantissa words decode huge as bf16
template <int NTH>
__device__ bool sniff_f32(const u16* x, float* red, int tid) {
  float m = 0.f;
  for (int i = tid; i < 1024; i += NTH) m = fmaxf(m, fabsf(b2f(x[i])));
  red[tid] = m;
  __syncthreads();
  if (tid < 32) {
    float mm = red[tid];
    for (int s = tid + 32; s < NTH; s += 32) mm = fmaxf(mm, red[s]);
    red[tid] = mm;
  }
  __syncthreads();
  if (tid == 0) {
    float mm = red[0];
    for (int s = 1; s < 32; ++s) mm = fmaxf(mm, red[s]);
    red[0] = mm;
  }
  __syncthreads();
  return red[0] > 1e8f;
}
}  // namespace

// ---------------- weight packing kernel (runs every launch) ----------------
template <bool F32>
__device__ void pack_body(const void* Wtok, const void* Wqkv, const void* Wproj,
                          const void* Wfrom, int gid) {
  const void* W; int Nw, base;
  if (gid < OFF_QKV)       { W = Wtok;  Nw = 128; base = OFF_TOK;  }
  else if (gid < OFF_PROJ) { W = Wqkv;  Nw = 384; base = OFF_QKV;  }
  else if (gid < OFF_FROM) { W = Wproj; Nw = 128; base = OFF_PROJ; }
  else                     { W = Wfrom; Nw = 128; base = OFF_FROM; }
  const int e = gid - base, chunk = e >> 9, rem = e & 511, lane = rem >> 3, j = rem & 7;
  const int ntile = chunk >> 2, kstep = chunk & 3;
  const int n = ntile * 16 + (lane & 15);
  const int k = kstep * 32 + (lane >> 4) * 8 + j;
  g_wpack[gid] = F32 ? f2b(((const float*)W)[k * Nw + n]) : ((const u16*)W)[k * Nw + n];
}

__global__ __launch_bounds__(256) void wan_pack_kernel(
    const void* x, const void* Wtok, const void* Wqkv, const void* Wproj,
    const void* Wfrom) {
  __shared__ float red[256];
  const int tid = threadIdx.x;
  const bool f32m = sniff_f32<256>((const u16*)x, red, tid);
  const int gid = blockIdx.x * 256 + tid;
  if (gid < WTOT) {
    if (f32m) pack_body<true>(Wtok, Wqkv, Wproj, Wfrom, gid);
    else      pack_body<false>(Wtok, Wqkv, Wproj, Wfrom, gid);
  }
}

// ---------------- main kernel ----------------
// One 512-thread block processes 4 consecutive t, packed as 96 rows
// (row = t*24 + joint). Row-wise GEMMs run once on M=96; attention is
// per-t on 32-row padded sub-blocks.
struct __align__(16) Smem {
  u16 xt[96 * AS];        // 26112 B  x (bf16) packed; residual source
  u16 tokb[96 * AS];      //          tok -> later O
  u16 qb[96 * AS];        //          q -> P overlay -> out2
  u16 kb[96 * AS];        //          k; y-slab overlay starts here
  u16 vt[NT * 128 * VS];  // 40960 B  v transposed per t [dim][token<32]
  float Sf[NT * 32 * SS]; // 17408 B  scores; sniff red[512]; norm partial[384]
};                        // 162816 B total -> 1 block/CU, 8 waves (2/SIMD)

// C[96 x 16] col-tile GEMM: C[:, cn*16..] = A[96x128] @ Wseg[ntile=ntw] + bias
template <bool F32>
__device__ __forceinline__ void rowGemm6(const u16* A, const u16* wseg, int ntw,
                                         int cn, const void* bias, u16* C,
                                         int l16, int quad, int lane) {
  const float bv = ld1<F32>(bias, ntw * 16 + l16);
  short8 bf[4];
  #pragma unroll
  for (int ks = 0; ks < 4; ++ks)
    bf[ks] = *(const short8*)(wseg + (ntw * 4 + ks) * 512 + lane * 8);
  #pragma unroll
  for (int mt = 0; mt < 6; ++mt) {
    f32x4 acc = {bv, bv, bv, bv};
    const u16* arow = A + (mt * 16 + l16) * AS + quad * 8;
    #pragma unroll
    for (int ks = 0; ks < 4; ++ks)
      acc = mfma16(*(const short8*)(arow + ks * 32), bf[ks], acc);
    u16* p = C + (mt * 16 + quad * 4) * AS + cn * 16 + l16;
    p[0] = f2b(acc[0]); p[AS] = f2b(acc[1]);
    p[2 * AS] = f2b(acc[2]); p[3 * AS] = f2b(acc[3]);
  }
}

template <bool F32>
__device__ void main_body(Smem& s, int tid, long long xbase, const void* x,
                          const void* btok, const void* gnorm, const void* bqkv,
                          const void* bproj, const void* bfrom, void* y) {
  const int lane = tid & 63, w = tid >> 6;       // w = wave id 0..7
  const int l16 = lane & 15, quad = lane >> 4;

  // ---- zero vt pad tokens 24..31 (avoid NaN in O's B-frags) ------------
  {
    const int t = tid >> 7, dim = tid & 127;
    u16* p = s.vt + (t * 128 + dim) * VS + 24;
    #pragma unroll
    for (int q = 0; q < 8; ++q) p[q] = 0;
  }

  // ---- stage x -> xt: 16B contiguous global read per channel -----------
  if (F32) {
    const float* xf = (const float*)x + xbase;
    #pragma unroll
    for (int m = 0; m < 6; ++m) {
      const int c = tid + 512 * m;
      const float4 v = *(const float4*)(xf + (long long)c * Tc);
      const int j = c >> 7, col = c & 127;
      s.xt[(0 * 24 + j) * AS + col] = f2b(v.x);
      s.xt[(1 * 24 + j) * AS + col] = f2b(v.y);
      s.xt[(2 * 24 + j) * AS + col] = f2b(v.z);
      s.xt[(3 * 24 + j) * AS + col] = f2b(v.w);
    }
  } else {
    const u16* xh = (const u16*)x + xbase;
    #pragma unroll
    for (int m = 0; m < 6; ++m) {
      const int c = tid + 512 * m;
      const ushort4 v = *(const ushort4*)(xh + (long long)c * Tc);
      const int j = c >> 7, col = c & 127;
      s.xt[(0 * 24 + j) * AS + col] = v.x;
      s.xt[(1 * 24 + j) * AS + col] = v.y;
      s.xt[(2 * 24 + j) * AS + col] = v.z;
      s.xt[(3 * 24 + j) * AS + col] = v.w;
    }
  }
  __syncthreads();

  // ---- tok = xt @ Wtok + btok (M=96, once for all 4 t) -----------------
  rowGemm6<F32>(s.xt, g_wpack + OFF_TOK, w, w, btok, s.tokb, l16, quad, lane);
  __syncthreads();

  // ---- RMSNorm 96 rows (4 threads/row x 32 cols, in-place bf16) --------
  if (tid < 384) {
    const int row = tid >> 2, sub = tid & 3;
    const u16* p = s.tokb + row * AS + sub * 32;
    float ss = 0.f;
    #pragma unroll
    for (int d = 0; d < 32; ++d) { const float v = b2f(p[d]); ss += v * v; }
    s.Sf[tid] = ss;
  }
  __syncthreads();
  if (tid < 384) {
    const int row = tid >> 2, sub = tid & 3;
    const float ss = s.Sf[row * 4 + 0] + s.Sf[row * 4 + 1] +
                     s.Sf[row * 4 + 2] + s.Sf[row * 4 + 3];
    const float rs = rsqrtf(ss * (1.0f / TD) + EPS);
    u16* p = s.tokb + row * AS + sub * 32;
    #pragma unroll
    for (int d = 0; d < 32; ++d)
      p[d] = f2b(b2f(p[d]) * rs * ld1<F32>(gnorm, sub * 32 + d));
  }
  __syncthreads();

  // ---- qkv = tok @ Wqkv + bqkv: wave w owns q/k/v dim-tile w -----------
  rowGemm6<F32>(s.tokb, g_wpack + OFF_QKV, w, w, bqkv, s.qb, l16, quad, lane);
  rowGemm6<F32>(s.tokb, g_wpack + OFF_QKV, 8 + w, w, bqkv, s.kb, l16, quad, lane);
  {  // v: scatter into per-t transposed vt[t][dim][localtok]
    const u16* wseg = g_wpack + OFF_QKV;
    const int ntw = 16 + w;
    const float bv = ld1<F32>(bqkv, ntw * 16 + l16);
    short8 bf[4];
    #pragma unroll
    for (int ks = 0; ks < 4; ++ks)
      bf[ks] = *(const short8*)(wseg + (ntw * 4 + ks) * 512 + lane * 8);
    #pragma unroll
    for (int mt = 0; mt < 6; ++mt) {
      f32x4 acc = {bv, bv, bv, bv};
      const u16* arow = s.tokb + (mt * 16 + l16) * AS + quad * 8;
      #pragma unroll
      for (int ks = 0; ks < 4; ++ks)
        acc = mfma16(*(const short8*)(arow + ks * 32), bf[ks], acc);
      #pragma unroll
      for (int r = 0; r < 4; ++r) {
        const int token = mt * 16 + quad * 4 + r;
        const int t = div24(token), lt = token - t * 24;
        s.vt[(t * 128 + w * 16 + l16) * VS + lt] = f2b(acc[r]);
      }
    }
  }
  __syncthreads();

  // ---- S = q @ k^T * SCALE, per t (wave w: t=w>>1, row-tile mt=w&1) ----
  {
    const int t = w >> 1, mt = w & 1;
    const u16* qrow = s.qb + (t * 24 + mt * 16 + l16) * AS + quad * 8;
    #pragma unroll
    for (int nt = 0; nt < 2; ++nt) {
      const u16* krow = s.kb + (t * 24 + nt * 16 + l16) * AS + quad * 8;
      f32x4 acc = {0.f, 0.f, 0.f, 0.f};
      #pragma unroll
      for (int ks = 0; ks < 4; ++ks)
        acc = mfma16(*(const short8*)(qrow + ks * 32),
                     *(const short8*)(krow + ks * 32), acc);
      // rows/cols >=24 contain cross-t garbage; masked downstream
      float* sp = s.Sf + (t * 32 + mt * 16 + quad * 4) * SS + nt * 16 + l16;
      sp[0] = acc[0] * SCALE; sp[SS] = acc[1] * SCALE;
      sp[2 * SS] = acc[2] * SCALE; sp[3 * SS] = acc[3] * SCALE;
    }
  }
  __syncthreads();

  // ---- softmax 96 rows -> P (bf16, overlay on dead q region) -----------
  // P[t][row<32][tok<32], stride VS, rows>=24 and cols>=24 zeroed.
  {
    u16* Pb = s.qb;
    if (tid < 96) {
      const int t = div24(tid), r = tid - t * 24;
      const float* sr = s.Sf + (t * 32 + r) * SS;
      float mx = -1e30f;
      #pragma unroll
      for (int jj = 0; jj < 24; ++jj) mx = fmaxf(mx, sr[jj]);
      float e[24]; float sum = 0.f;
      #pragma unroll
      for (int jj = 0; jj < 24; ++jj) { e[jj] = __expf(sr[jj] - mx); sum += e[jj]; }
      const float inv = 1.0f / sum;
      u16* pr = Pb + (t * 32 + r) * VS;
      #pragma unroll
      for (int jj = 0; jj < 24; ++jj) pr[jj] = f2b(e[jj] * inv);
      #pragma unroll
      for (int jj = 24; jj < 32; ++jj) pr[jj] = 0;
    } else if (tid < 128) {
      const int i = tid - 96, t = i >> 3, r = 24 + (i & 7);
      u16* pr = Pb + (t * 32 + r) * VS;
      #pragma unroll
      for (int jj = 0; jj < 32; ++jj) pr[jj] = 0;
    }
  }
  __syncthreads();

  // ---- O = P @ v (K=32, 1 MFMA/tile) -> tokb (mask pad rows) -----------
  {
    const u16* Pb = s.qb;
    const int t = w >> 1, mt = w & 1;
    const short8 ap = *(const short8*)(Pb + (t * 32 + mt * 16 + l16) * VS + quad * 8);
    #pragma unroll
    for (int nt = 0; nt < 8; ++nt) {
      const short8 bv =
          *(const short8*)(s.vt + (t * 128 + nt * 16 + l16) * VS + quad * 8);
      f32x4 acc = {0.f, 0.f, 0.f, 0.f};
      acc = mfma16(ap, bv, acc);
      u16* p = s.tokb + (t * 24 + mt * 16 + quad * 4) * AS + nt * 16 + l16;
      #pragma unroll
      for (int r = 0; r < 4; ++r)
        if (mt * 16 + quad * 4 + r < 24) p[r * AS] = f2b(acc[r]);
    }
  }
  __syncthreads();

  // ---- out2 = O @ Wproj + bproj -> qb (P dead) -------------------------
  rowGemm6<F32>(s.tokb, g_wpack + OFF_PROJ, w, w, bproj, s.qb, l16, quad, lane);
  __syncthreads();

  // ---- out3 = out2 @ Wfrom + bfrom; stage y = x + out3 into slab -------
  // slab overlays dead kb+vt (67072 B >= 49152 B needed for f32)
  {
    float* slabf = (float*)s.kb;
    u16*   slabh = (u16*)s.kb;
    const u16* wseg = g_wpack + OFF_FROM;
    const float bv = ld1<F32>(bfrom, w * 16 + l16);
    short8 bf[4];
    #pragma unroll
    for (int ks = 0; ks < 4; ++ks)
      bf[ks] = *(const short8*)(wseg + (w * 4 + ks) * 512 + lane * 8);
    #pragma unroll
    for (int mt = 0; mt < 6; ++mt) {
      f32x4 acc = {bv, bv, bv, bv};
      const u16* arow = s.qb + (mt * 16 + l16) * AS + quad * 8;
      #pragma unroll
      for (int ks = 0; ks < 4; ++ks)
        acc = mfma16(*(const short8*)(arow + ks * 32), bf[ks], acc);
      #pragma unroll
      for (int r = 0; r < 4; ++r) {
        const int row = mt * 16 + quad * 4 + r;
        const int t = div24(row), jr = row - t * 24;
        const int cc = w * 16 + l16;
        const int ch = jr * CPJ + cc;
        const float res = b2f(s.xt[row * AS + cc]) + acc[r];
        if (F32) slabf[t * 3072 + slot(ch)] = res;
        else     slabh[t * 3072 + slot(ch)] = f2b(res);
      }
    }
  }
  __syncthreads();

  // ---- write out slab -> y: 16B contiguous per channel -----------------
  if (F32) {
    const float* slabf = (const float*)s.kb;
    float* yf = (float*)y + xbase;
    #pragma unroll
    for (int m = 0; m < 6; ++m) {
      const int c = tid + 512 * m;
      const int sc = slot(c);
      float4 a;
      a.x = slabf[0 * 3072 + sc]; a.y = slabf[1 * 3072 + sc];
      a.z = slabf[2 * 3072 + sc]; a.w = slabf[3 * 3072 + sc];
      *(float4*)(yf + (long long)c * Tc) = a;
    }
  } else {
    const u16* slabh = (const u16*)s.kb;
    u16* yh = (u16*)y + xbase;
    #pragma unroll
    for (int m = 0; m < 6; ++m) {
      const int c = tid + 512 * m;
      const int sc = slot(c);
      ushort4 v;
      v.x = slabh[0 * 3072 + sc]; v.y = slabh[1 * 3072 + sc];
      v.z = slabh[2 * 3072 + sc]; v.w = slabh[3 * 3072 + sc];
      *(ushort4*)(yh + (long long)c * Tc) = v;
    }
  }
}

__global__ __launch_bounds__(512, 2) void wan_main_kernel(
    const void* x, const void* btok, const void* gnorm, const void* bqkv,
    const void* bproj, const void* bfrom, void* y) {
  __shared__ Smem s;
  const int tid = threadIdx.x;
  // XCD-aware swizzle over t-quads: 4096 blocks = 8 XCDs x 512 contiguous
  // quads, so adjacent-t blocks share an XCD L2 for read/write line merge.
  const int id = blockIdx.x;
  const int q = (id & 7) * 512 + (id >> 3);
  const int b = q >> 10, t0 = (q & 1023) << 2;
  const long long xbase = (long long)b * (Kc * CPJ) * Tc + t0;

  const bool f32m = sniff_f32<512>((const u16*)x, s.Sf, tid);
  if (f32m)
    main_body<true>(s, tid, xbase, x, btok, gnorm, bqkv, bproj, bfrom, y);
  else
    main_body<false>(s, tid, xbase, x, btok, gnorm, bqkv, bproj, bfrom, y);
}

extern "C" void kernel_launch(void* const* d_in, const int* in_sizes, int n_in,
                              void* d_out, int out_size, void* d_ws, size_t ws_size,
                              hipStream_t stream) {
  wan_pack_kernel<<<384, 256, 0, stream>>>(d_in[0], d_in[1], d_in[4], d_in[6],
                                           d_in[8]);
  wan_main_kernel<<<4096, 512, 0, stream>>>(d_in[0], d_in[2], d_in[3], d_in[5],
                                            d_in[7], d_in[9], d_out);
}